// Round 3
// baseline (446.582 us; speedup 1.0000x reference)
//
#include <hip/hip_runtime.h>

#define HW_ 4096
#define KSEL 409     // int(0.1 * 4096)
#define NCAND 256    // max candidates handled by register radix-select (4/lane * 64)
#define LISTCAP 512  // LDS candidate list capacity (guarded)

// Parallel top-down crossing search over an N-bin histogram in LDS (wave 0 only).
// Finds largest bin b such that count(bins > b) < kneed <= count(bins >= b).
// Writes *s_bin = b, *s_rem = kneed - count(bins > b).
template <int N>
__device__ __forceinline__ void scan_find(const unsigned* hist, unsigned kneed,
                                          unsigned* s_bin, unsigned* s_rem, int t) {
  constexpr int C = N >> 6;  // bins per lane (32 for N=2048, 16 for N=1024)
  if (t < 64) {
    const int base = N - (t + 1) * C;  // lane 0 covers the TOP chunk
    const uint4* hp = (const uint4*)(hist + base);
    unsigned sum = 0;
    // Rotate read order by lane so different lanes hit different bank groups.
    const int rot = t & ((C / 4) - 1);
    #pragma unroll
    for (int j = 0; j < C / 4; ++j) {
      int jj = j + rot;
      if (jj >= C / 4) jj -= C / 4;
      uint4 u = hp[jj];
      sum += u.x + u.y + u.z + u.w;
    }
    unsigned inc = sum;
    #pragma unroll
    for (int off = 1; off < 64; off <<= 1) {
      unsigned u = __shfl_up(inc, off);
      if (t >= off) inc += u;
    }
    unsigned long long mb = __ballot(inc >= kneed);
    int cl = __ffsll((unsigned long long)mb) - 1;  // topmost crossing chunk
    unsigned cumAbove = __shfl(inc, cl) - __shfl(sum, cl);
    int cbase = N - (cl + 1) * C;
    unsigned hval = (t < C) ? hist[cbase + (C - 1 - t)] : 0u;
    unsigned inc2 = hval;
    #pragma unroll
    for (int off = 1; off < 64; off <<= 1) {
      unsigned u = __shfl_up(inc2, off);
      if (t >= off) inc2 += u;
    }
    unsigned long long mb2 = __ballot(cumAbove + inc2 >= kneed);
    int cl2 = __ffsll((unsigned long long)mb2) - 1;
    if (t == cl2) {
      *s_bin = (unsigned)(cbase + (C - 1 - t));
      *s_rem = kneed - (cumAbove + inc2 - hval);
    }
  }
}

// Everything after the pass-1 histogram atomics for one row:
// scan -> compact -> register radix-select (fallback: hist passes) -> mask -> store.
// Precondition: hist holds the row's 2048-bin histogram (atomics done, no barrier yet),
// cnt == 0. Leaves hist/cnt dirty.
__device__ __forceinline__ void finish_row(const float4 (&v)[4], unsigned* hist,
                                           unsigned* clist, unsigned* sb,
                                           unsigned* cntp, int t, float4* orow) {
  unsigned ab[16];
  #pragma unroll
  for (int j = 0; j < 4; ++j) {
    ab[4 * j + 0] = __float_as_uint(v[j].x) & 0x7FFFFFFFu;
    ab[4 * j + 1] = __float_as_uint(v[j].y) & 0x7FFFFFFFu;
    ab[4 * j + 2] = __float_as_uint(v[j].z) & 0x7FFFFFFFu;
    ab[4 * j + 3] = __float_as_uint(v[j].w) & 0x7FFFFFFFu;
  }
  __syncthreads();  // histogram atomics complete
  scan_find<2048>(hist, KSEL, &sb[0], &sb[1], t);
  __syncthreads();
  const unsigned b1 = sb[0];
  const unsigned k2 = sb[1];

  // compact candidates (elements in threshold bin b1) into LDS list
  #pragma unroll
  for (int i = 0; i < 16; ++i) {
    if ((ab[i] >> 20) == b1) {
      unsigned id = atomicAdd(cntp, 1u);
      if (id < LISTCAP) clist[id] = ab[i];
    }
  }
  __syncthreads();
  const unsigned m = *cntp;  // block-uniform

  unsigned T, rem, ceq;
  if (m <= NCAND) {
    // register radix-select of k2-th largest low-20-bit value (wave 0)
    if (t < 64) {
      unsigned rq[4];
      bool vq[4];
      #pragma unroll
      for (int q = 0; q < 4; ++q) {
        unsigned idx = (unsigned)t + 64u * q;
        vq[q] = idx < m;
        rq[q] = vq[q] ? (clist[idx] & 0xFFFFFu) : 0u;
      }
      unsigned p = 0, need = k2;
      #pragma unroll
      for (int b = 19; b >= 0; --b) {
        unsigned trial = p | (1u << b);
        unsigned c = 0;
        #pragma unroll
        for (int q = 0; q < 4; ++q) {
          bool pr = vq[q] && ((rq[q] >> b) == (trial >> b));
          c += (unsigned)__popcll(__ballot(pr));
        }
        if (c >= need) p = trial;
        else need -= c;
      }
      unsigned ce = 0;
      #pragma unroll
      for (int q = 0; q < 4; ++q)
        ce += (unsigned)__popcll(__ballot(vq[q] && (rq[q] == p)));
      if (t == 0) { sb[0] = p; sb[1] = need; sb[2] = ce; }
    }
    __syncthreads();
    T = (b1 << 20) | sb[0];
    rem = sb[1];
    ceq = sb[2];
  } else {
    // fallback (exactness guard, statistically never taken): histogram passes
    const uint4 z4 = make_uint4(0u, 0u, 0u, 0u);
    __syncthreads();
    ((uint4*)hist)[t] = z4;  // zero 1024 bins (256 threads x 4)
    __syncthreads();
    #pragma unroll
    for (int i = 0; i < 16; ++i)
      if ((ab[i] >> 20) == b1) atomicAdd(&hist[(ab[i] >> 10) & 0x3FFu], 1u);
    __syncthreads();
    scan_find<1024>(hist, k2, &sb[0], &sb[1], t);
    __syncthreads();
    const unsigned b2 = sb[0];
    const unsigned k3 = sb[1];
    const unsigned P = (b1 << 10) | b2;
    __syncthreads();
    ((uint4*)hist)[t] = z4;
    __syncthreads();
    #pragma unroll
    for (int i = 0; i < 16; ++i)
      if ((ab[i] >> 10) == P) atomicAdd(&hist[ab[i] & 0x3FFu], 1u);
    __syncthreads();
    scan_find<1024>(hist, k3, &sb[0], &sb[1], t);
    __syncthreads();
    T = (P << 10) | sb[0];
    rem = sb[1];
    ceq = hist[sb[0]];
  }

  unsigned keepmask = 0;
  #pragma unroll
  for (int i = 0; i < 16; ++i)
    if (ab[i] > T) keepmask |= (1u << i);

  if (rem == ceq) {
    #pragma unroll
    for (int i = 0; i < 16; ++i)
      if (ab[i] == T) keepmask |= (1u << i);
  } else {
    // Rare exact-bitwise-tie path: keep the first `rem` equals in index order.
    // Element index = 4*t + 1024*j + e -> lexicographic (j, t, e).
    __syncthreads();  // all threads have read T/rem/ceq before hist is reused
    #pragma unroll
    for (int j = 0; j < 4; ++j) {
      unsigned c = 0;
      #pragma unroll
      for (int e = 0; e < 4; ++e)
        if (ab[4 * j + e] == T) ++c;
      hist[j * 256 + t] = c;
    }
    __syncthreads();
    if (t == 0) {  // serial exclusive prefix in index order (rare path)
      unsigned run = 0;
      for (int i = 0; i < 1024; ++i) { unsigned h = hist[i]; hist[i] = run; run += h; }
    }
    __syncthreads();
    #pragma unroll
    for (int j = 0; j < 4; ++j) {
      unsigned r = hist[j * 256 + t];
      #pragma unroll
      for (int e = 0; e < 4; ++e) {
        if (ab[4 * j + e] == T) {
          if (r < rem) keepmask |= (1u << (4 * j + e));
          ++r;
        }
      }
    }
  }

  // write out (coalesced float4); fire-and-forget
  #pragma unroll
  for (int j = 0; j < 4; ++j) {
    float4 o;
    o.x = ((keepmask >> (4 * j + 0)) & 1u) ? v[j].x : 0.0f;
    o.y = ((keepmask >> (4 * j + 1)) & 1u) ? v[j].y : 0.0f;
    o.z = ((keepmask >> (4 * j + 2)) & 1u) ? v[j].z : 0.0f;
    o.w = ((keepmask >> (4 * j + 3)) & 1u) ? v[j].w : 0.0f;
    orow[t + j * 256] = o;
  }
}

// Two rows per block, software-pipelined: row B's global loads are issued while
// row A is in its scan/select phases, so HBM stays busy through the serial bubble.
extern "C" __global__ void __launch_bounds__(256, 4)
topk_kern(const float* __restrict__ x, float* __restrict__ out) {
  __shared__ __align__(16) unsigned hist[2048];
  __shared__ unsigned sb[3];
  __shared__ unsigned cnt;
  __shared__ unsigned clist[LISTCAP];
  const int t = threadIdx.x;
  const size_t rowoffA = (size_t)blockIdx.x * (2 * HW_);
  const float4* xrA = (const float4*)(x + rowoffA);
  const float4* xrB = xrA + (HW_ / 4);
  float4* orowA = (float4*)(out + rowoffA);
  float4* orowB = orowA + (HW_ / 4);

  // ---- row A: load ----
  float4 vA[4], vB[4];
  #pragma unroll
  for (int j = 0; j < 4; ++j) vA[j] = xrA[t + j * 256];

  const uint4 z4 = make_uint4(0u, 0u, 0u, 0u);
  ((uint4*)hist)[t] = z4;        // zero all 2048 bins (256 threads x 2 stores)
  ((uint4*)hist)[t + 256] = z4;
  if (t == 0) cnt = 0;
  __syncthreads();

  // ---- row A: pass-1 histogram atomics ----
  #pragma unroll
  for (int j = 0; j < 4; ++j) {
    atomicAdd(&hist[(__float_as_uint(vA[j].x) & 0x7FFFFFFFu) >> 20], 1u);
    atomicAdd(&hist[(__float_as_uint(vA[j].y) & 0x7FFFFFFFu) >> 20], 1u);
    atomicAdd(&hist[(__float_as_uint(vA[j].z) & 0x7FFFFFFFu) >> 20], 1u);
    atomicAdd(&hist[(__float_as_uint(vA[j].w) & 0x7FFFFFFFu) >> 20], 1u);
  }

  // ---- issue row B loads: in flight during A's scan/compact/select/store ----
  #pragma unroll
  for (int j = 0; j < 4; ++j) vB[j] = xrB[t + j * 256];

  // ---- row A: scan -> select -> mask -> store ----
  finish_row(vA, hist, clist, sb, &cnt, t, orowA);

  // ---- reset LDS for row B ----
  __syncthreads();  // all LDS reads of A's select/tie path done
  ((uint4*)hist)[t] = z4;
  ((uint4*)hist)[t + 256] = z4;
  if (t == 0) cnt = 0;
  __syncthreads();

  // ---- row B: pass-1 histogram atomics (loads long since landed) ----
  #pragma unroll
  for (int j = 0; j < 4; ++j) {
    atomicAdd(&hist[(__float_as_uint(vB[j].x) & 0x7FFFFFFFu) >> 20], 1u);
    atomicAdd(&hist[(__float_as_uint(vB[j].y) & 0x7FFFFFFFu) >> 20], 1u);
    atomicAdd(&hist[(__float_as_uint(vB[j].z) & 0x7FFFFFFFu) >> 20], 1u);
    atomicAdd(&hist[(__float_as_uint(vB[j].w) & 0x7FFFFFFFu) >> 20], 1u);
  }

  // ---- row B: scan -> select -> mask -> store ----
  finish_row(vB, hist, clist, sb, &cnt, t, orowB);
}

extern "C" void kernel_launch(void* const* d_in, const int* in_sizes, int n_in,
                              void* d_out, int out_size, void* d_ws, size_t ws_size,
                              hipStream_t stream) {
  const float* x = (const float*)d_in[0];
  float* out = (float*)d_out;
  const int rows = in_sizes[0] / HW_;  // 64*256 = 16384 rows of 4096
  topk_kern<<<dim3(rows / 2), dim3(256), 0, stream>>>(x, out);
}

// Round 4
// 432.750 us; speedup vs baseline: 1.0320x; 1.0320x over previous
//
#include <hip/hip_runtime.h>

#define HW_ 4096
#define KSEL 409     // int(0.1 * 4096)
#define NCAND 256    // max candidates handled by register radix-select (4/lane * 64)
#define LISTCAP 512  // LDS candidate list capacity (guarded)

// Parallel top-down crossing search over an N-bin histogram in LDS (wave 0 only).
// Finds largest bin b such that count(bins > b) < kneed <= count(bins >= b).
// Writes *s_bin = b, *s_rem = kneed - count(bins > b).
template <int N>
__device__ __forceinline__ void scan_find(const unsigned* hist, unsigned kneed,
                                          unsigned* s_bin, unsigned* s_rem, int t) {
  constexpr int C = N >> 6;  // bins per lane (32 for N=2048)
  if (t < 64) {
    const int base = N - (t + 1) * C;  // lane 0 covers the TOP chunk
    const uint4* hp = (const uint4*)(hist + base);  // 16B-aligned
    unsigned sum = 0;
    // Rotate read order by lane so different lanes hit different bank groups
    // (unrotated: all 64 lanes read the same 4 banks per j -> 16-way conflict).
    const int rot = t & ((C / 4) - 1);
    #pragma unroll
    for (int j = 0; j < C / 4; ++j) {
      int jj = j + rot;
      if (jj >= C / 4) jj -= C / 4;
      uint4 u = hp[jj];
      sum += u.x + u.y + u.z + u.w;
    }
    // inclusive scan of chunk sums, lane 0 = top
    unsigned inc = sum;
    #pragma unroll
    for (int off = 1; off < 64; off <<= 1) {
      unsigned u = __shfl_up(inc, off);
      if (t >= off) inc += u;
    }
    unsigned long long mb = __ballot(inc >= kneed);
    int cl = __ffsll((unsigned long long)mb) - 1;  // topmost crossing chunk (uniform)
    unsigned cumAbove = __shfl(inc, cl) - __shfl(sum, cl);  // count strictly above chunk cl
    int cbase = N - (cl + 1) * C;
    // parallel within-chunk: lane j reads one bin (top-down), scan, ballot
    unsigned hval = (t < C) ? hist[cbase + (C - 1 - t)] : 0u;
    unsigned inc2 = hval;
    #pragma unroll
    for (int off = 1; off < 64; off <<= 1) {
      unsigned u = __shfl_up(inc2, off);
      if (t >= off) inc2 += u;
    }
    unsigned long long mb2 = __ballot(cumAbove + inc2 >= kneed);
    int cl2 = __ffsll((unsigned long long)mb2) - 1;
    if (t == cl2) {
      *s_bin = (unsigned)(cbase + (C - 1 - t));
      *s_rem = kneed - (cumAbove + inc2 - hval);
    }
  }
}

extern "C" __global__ void __launch_bounds__(256, 4)
topk_kern(const float* __restrict__ x, float* __restrict__ out) {
  __shared__ __align__(16) unsigned hist[2048];
  __shared__ unsigned sb[3];
  __shared__ unsigned cnt;
  __shared__ unsigned clist[LISTCAP];
  const int t = threadIdx.x;
  const size_t rowoff = (size_t)blockIdx.x * HW_;
  const float4* xr = (const float4*)(x + rowoff);
  float4* orow = (float4*)(out + rowoff);

  // Load 16 elements per thread as 4x float4 (coalesced), keep in registers.
  float4 v[4];
  unsigned ab[16];
  #pragma unroll
  for (int j = 0; j < 4; ++j) {
    v[j] = xr[t + j * 256];
    ab[4 * j + 0] = __float_as_uint(v[j].x) & 0x7FFFFFFFu;
    ab[4 * j + 1] = __float_as_uint(v[j].y) & 0x7FFFFFFFu;
    ab[4 * j + 2] = __float_as_uint(v[j].z) & 0x7FFFFFFFu;
    ab[4 * j + 3] = __float_as_uint(v[j].w) & 0x7FFFFFFFu;
  }

  // ---- pass 1: top 11 bits (ab>>20), 2048 bins ----
  const uint4 z4 = make_uint4(0u, 0u, 0u, 0u);
  ((uint4*)hist)[t] = z4;          // 2 x ds_write_b128 zeroes all 2048 bins
  ((uint4*)hist)[t + 256] = z4;
  if (t == 0) cnt = 0;
  __syncthreads();
  #pragma unroll
  for (int i = 0; i < 16; ++i) atomicAdd(&hist[ab[i] >> 20], 1u);
  __syncthreads();
  scan_find<2048>(hist, KSEL, &sb[0], &sb[1], t);
  __syncthreads();
  const unsigned b1 = sb[0];
  const unsigned k2 = sb[1];

  // ---- compact candidates (elements in threshold bin b1) into LDS list ----
  #pragma unroll
  for (int i = 0; i < 16; ++i) {
    if ((ab[i] >> 20) == b1) {
      unsigned id = atomicAdd(&cnt, 1u);
      if (id < LISTCAP) clist[id] = ab[i];
    }
  }
  __syncthreads();
  const unsigned m = cnt;  // block-uniform

  unsigned T, rem, ceq;
  if (m <= NCAND) {
    // ---- register radix-select of k2-th largest low-20-bit value (wave 0) ----
    if (t < 64) {
      unsigned rq[4];
      bool vq[4];
      #pragma unroll
      for (int q = 0; q < 4; ++q) {
        unsigned idx = (unsigned)t + 64u * q;
        vq[q] = idx < m;
        rq[q] = vq[q] ? (clist[idx] & 0xFFFFFu) : 0u;
      }
      unsigned p = 0, need = k2;
      #pragma unroll
      for (int b = 19; b >= 0; --b) {
        unsigned trial = p | (1u << b);
        unsigned c = 0;
        #pragma unroll
        for (int q = 0; q < 4; ++q) {
          bool pr = vq[q] && ((rq[q] >> b) == (trial >> b));
          c += (unsigned)__popcll(__ballot(pr));
        }
        if (c >= need) p = trial;
        else need -= c;
      }
      unsigned ce = 0;
      #pragma unroll
      for (int q = 0; q < 4; ++q)
        ce += (unsigned)__popcll(__ballot(vq[q] && (rq[q] == p)));
      if (t == 0) { sb[0] = p; sb[1] = need; sb[2] = ce; }
    }
    __syncthreads();
    T = (b1 << 20) | sb[0];
    rem = sb[1];
    ceq = sb[2];
  } else {
    // ---- fallback (exactness guard, statistically never taken): histogram passes ----
    ((uint4*)hist)[t] = z4;  // zero 1024 bins
    __syncthreads();
    #pragma unroll
    for (int i = 0; i < 16; ++i)
      if ((ab[i] >> 20) == b1) atomicAdd(&hist[(ab[i] >> 10) & 0x3FFu], 1u);
    __syncthreads();
    scan_find<1024>(hist, k2, &sb[0], &sb[1], t);
    __syncthreads();
    const unsigned b2 = sb[0];
    const unsigned k3 = sb[1];
    const unsigned P = (b1 << 10) | b2;
    __syncthreads();
    ((uint4*)hist)[t] = z4;
    __syncthreads();
    #pragma unroll
    for (int i = 0; i < 16; ++i)
      if ((ab[i] >> 10) == P) atomicAdd(&hist[ab[i] & 0x3FFu], 1u);
    __syncthreads();
    scan_find<1024>(hist, k3, &sb[0], &sb[1], t);
    __syncthreads();
    T = (P << 10) | sb[0];
    rem = sb[1];
    ceq = hist[sb[0]];
  }

  unsigned keepmask = 0;
  #pragma unroll
  for (int i = 0; i < 16; ++i)
    if (ab[i] > T) keepmask |= (1u << i);

  if (rem == ceq) {
    // no tie truncation needed: keep every element equal to T
    #pragma unroll
    for (int i = 0; i < 16; ++i)
      if (ab[i] == T) keepmask |= (1u << i);
  } else {
    // Rare exact-bitwise-tie path: keep the first `rem` equals in index order.
    // Element index = 4*t + 1024*j + e -> lexicographic (j, t, e).
    __syncthreads();  // all threads have read T/rem/ceq before hist is reused
    #pragma unroll
    for (int j = 0; j < 4; ++j) {
      unsigned c = 0;
      #pragma unroll
      for (int e = 0; e < 4; ++e)
        if (ab[4 * j + e] == T) ++c;
      hist[j * 256 + t] = c;
    }
    __syncthreads();
    if (t == 0) {  // serial exclusive prefix in index order (rare path)
      unsigned run = 0;
      for (int i = 0; i < 1024; ++i) { unsigned h = hist[i]; hist[i] = run; run += h; }
    }
    __syncthreads();
    #pragma unroll
    for (int j = 0; j < 4; ++j) {
      unsigned r = hist[j * 256 + t];
      #pragma unroll
      for (int e = 0; e < 4; ++e) {
        if (ab[4 * j + e] == T) {
          if (r < rem) keepmask |= (1u << (4 * j + e));
          ++r;
        }
      }
    }
  }

  // ---- write out (coalesced float4) ----
  #pragma unroll
  for (int j = 0; j < 4; ++j) {
    float4 o;
    o.x = ((keepmask >> (4 * j + 0)) & 1u) ? v[j].x : 0.0f;
    o.y = ((keepmask >> (4 * j + 1)) & 1u) ? v[j].y : 0.0f;
    o.z = ((keepmask >> (4 * j + 2)) & 1u) ? v[j].z : 0.0f;
    o.w = ((keepmask >> (4 * j + 3)) & 1u) ? v[j].w : 0.0f;
    orow[t + j * 256] = o;
  }
}

extern "C" void kernel_launch(void* const* d_in, const int* in_sizes, int n_in,
                              void* d_out, int out_size, void* d_ws, size_t ws_size,
                              hipStream_t stream) {
  const float* x = (const float*)d_in[0];
  float* out = (float*)d_out;
  const int rows = in_sizes[0] / HW_;  // 64*256 = 16384 rows of 4096
  topk_kern<<<dim3(rows), dim3(256), 0, stream>>>(x, out);
}